// Round 8
// baseline (238.817 us; speedup 1.0000x reference)
//
#include <hip/hip_runtime.h>
#include <stdint.h>

// ConcatLayer_55654186221983 on MI355X (gfx950). All fp32 I/O.
// B=8, C=128, C2=256, H=W=64, EMB=512, GROUPS=32, EPS=1e-5.
// R17 (on R15's 216us; R16 remap reverted): half-row tiles. Conv blocks
//      split into x-halves (tile 3x40x272B = 32.6KB, 4-px halos, 256 thr /
//      4 waves = 4 och-groups). conv1/2: 4 blocks/CU (was 2) -> 4 indep
//      barrier domains at same 16 waves/CU. bconv: gload_lds 3x10KB rows,
//      30.7KB LDS, launch_bounds(256,5) -> up to 20 waves/CU.

#define B_   8
#define C_   128
#define C2_  256
#define HW_  4096
#define EMB_ 512
#define EPS_ 1e-5f

typedef int   v16i __attribute__((ext_vector_type(16)));
typedef float v16f __attribute__((ext_vector_type(16)));
typedef short v8s  __attribute__((ext_vector_type(8)));
typedef int   v4i  __attribute__((ext_vector_type(4)));

#define COLB 272
#define ROWB (66 * COLB)          // 17952 B per padded S row
#define TW   40                   // conv tile cols (px window 32h-4 .. 32h+35)
#define CLDS (3 * TW * COLB)      // 32640 B conv tile
#define BROW 10240                // bconv LDS row pitch (>= 34*272 rounded to 1KB)
#define TSTRIDE 132

__device__ __forceinline__ float silu(float v) {
    return v * __builtin_amdgcn_rcpf(1.f + __expf(-v));
}
__device__ __forceinline__ unsigned short f2bf(float f) {
    unsigned int x = __float_as_uint(f);
    return (unsigned short)((x + 0x7FFFu + ((x >> 16) & 1u)) >> 16);  // RNE
}
__device__ __forceinline__ int8_t sgn8(float v) {
    return (v > 0.f) ? (int8_t)1 : ((v < 0.f) ? (int8_t)(-1) : (int8_t)0);
}
__device__ __forceinline__ void gld16(char* ldst, const char* gsrc) {
    __builtin_amdgcn_global_load_lds((const unsigned int*)gsrc,
                                     (unsigned int*)ldst, 16, 0, 0);
}

// ---- merged prep + embedding + GN1-stats-halves + S-guard-zero ----
__global__ __launch_bounds__(256) void k_prep(
    const float* __restrict__ w, int8_t* __restrict__ sgn,
    float* __restrict__ alpha, float* __restrict__ bnS, float* __restrict__ bnQ,
    float* __restrict__ gnS, float* __restrict__ gnQ,
    const float* __restrict__ w1, const float* __restrict__ w2,
    unsigned short* __restrict__ Wc1, unsigned short* __restrict__ Wc2,
    const float* __restrict__ emb,
    const float* __restrict__ ew, const float* __restrict__ ebb,
    const float* __restrict__ m1w, const float* __restrict__ m1b,
    const float* __restrict__ m2w, const float* __restrict__ m2b,
    const float* __restrict__ m3w, const float* __restrict__ m3b,
    float* __restrict__ eo, float* __restrict__ b1,
    float* __restrict__ b2, float* __restrict__ b3,
    const float* __restrict__ gin,
    float* __restrict__ g1S, float* __restrict__ g1Q,
    int8_t* __restrict__ S) {
    __shared__ float red[256];
    const int blk = blockIdx.x, tid = threadIdx.x;
    if (blk < 128) {
        const int o = blk;
        if (o == 0 && tid < 128) { bnS[tid] = 0.f; bnQ[tid] = 0.f; }
        if (o == 1) { gnS[tid] = 0.f; }
        if (o == 2) { gnQ[tid] = 0.f; }
        const float* wr = w + (size_t)o * (C2_ * 9);
        float s = 0.f;
        for (int i = tid; i < C2_ * 9; i += 256) s += fabsf(wr[i]);
        red[tid] = s;
        __syncthreads();
        for (int st = 128; st > 0; st >>= 1) {
            if (tid < st) red[tid] += red[tid + st];
            __syncthreads();
        }
        if (tid == 0) alpha[o] = red[0] / (float)(C2_ * 9);
        for (int kk = 0; kk < 9; ++kk) {
            float v = wr[tid * 9 + kk];   // tid == ci
            sgn[((size_t)(kk * 16 + (tid >> 4)) * C_ + o) * 16 + (tid & 15)] = sgn8(v);
        }
    } else if (blk < 704) {
        int i = (blk - 128) * 256 + tid;
        int co = i / (C_ * 9);
        int rem = i - co * (C_ * 9);
        int ci = rem / 9, kk = rem - ci * 9;
        size_t d = ((size_t)(kk * 16 + (ci >> 3)) * C_ + co) * 8 + (ci & 7);
        Wc1[d] = f2bf(w1[i]);
        Wc2[d] = f2bf(w2[i]);
    } else if (blk < 896) {
        const int o = (blk - 704) * 4 + (tid >> 6);   // 0..767
        const int l = tid & 63;
        const float* wv;
        float bias;
        float* dst;
        int dstride;
        if (o < 256)      { wv = ew  + (size_t)o * EMB_;              bias = ebb[o];    dst = eo + o;  dstride = 256; }
        else if (o < 512) { int r = o - 256; wv = m1w + (size_t)r * EMB_; bias = m1b[r]; dst = b1 + r; dstride = 256; }
        else if (o < 640) { int r = o - 512; wv = m2w + (size_t)r * EMB_; bias = m2b[r]; dst = b2 + r; dstride = 128; }
        else              { int r = o - 640; wv = m3w + (size_t)r * EMB_; bias = m3b[r]; dst = b3 + r; dstride = 128; }
        const float4 wa = *(const float4*)(wv + 8 * l);
        const float4 wb = *(const float4*)(wv + 8 * l + 4);
#pragma unroll
        for (int b = 0; b < B_; ++b) {
            const float* s = emb + b * EMB_ + 8 * l;
            float4 sa = *(const float4*)(s);
            float4 sb = *(const float4*)(s + 4);
            float p = wa.x * silu(sa.x) + wa.y * silu(sa.y) + wa.z * silu(sa.z) + wa.w * silu(sa.w) +
                      wb.x * silu(sb.x) + wb.y * silu(sb.y) + wb.z * silu(sb.z) + wb.w * silu(sb.w);
#pragma unroll
            for (int off = 32; off > 0; off >>= 1) p += __shfl_down(p, off, 64);
            if (l == 0) dst[b * dstride] = bias + p;
        }
    } else if (blk < 1408) {
        // GN1 stats, hw-halves
        const int idx = blk - 896;
        const int n = idx >> 6, rest = idx & 63, grp = rest >> 1, h = rest & 1;
        const size_t base = ((size_t)(n * C_ + grp * 4)) << 12;
        float sum = 0.f, sq = 0.f;
        const float4* in4 = (const float4*)(gin + base);
        for (int i = tid + h * 2048; i < (h + 1) * 2048; i += 256) {
            float4 v = in4[i];
            sum += v.x + v.y + v.z + v.w;
            sq += v.x * v.x + v.y * v.y + v.z * v.z + v.w * v.w;
        }
#pragma unroll
        for (int off = 32; off > 0; off >>= 1) {
            sum += __shfl_xor(sum, off, 64);
            sq  += __shfl_xor(sq, off, 64);
        }
        if ((tid & 63) == 0) { red[tid >> 6] = sum; red[8 + (tid >> 6)] = sq; }
        __syncthreads();
        if (tid == 0) {
            g1S[h * 256 + n * 32 + grp] = red[0] + red[1] + red[2] + red[3];
            g1Q[h * 256 + n * 32 + grp] = red[8] + red[9] + red[10] + red[11];
        }
    } else {
        // zero S guard rows (row 0 and row 65 per n)
        const int u = blk - 1408;       // 0..15
        const int n = u >> 1;
        const int row = (u & 1) * 65;
        int4* base = (int4*)(S + (size_t)n * 66 * ROWB + (size_t)row * ROWB);
        const int4 z = make_int4(0, 0, 0, 0);
        for (int i = tid; i < ROWB / 16; i += 256) base[i] = z;
    }
}

// ---- conv1: half-row tile; GN1+SiLU+bf16 staging; bf16 MFMA; GN2 stats;
//      writes y NHWC fp32. block = (y*2+h, n); 256 thr, wave = og. ----
__global__ __launch_bounds__(256, 4) void k_conv1(
    const float* __restrict__ cin,
    const unsigned short* __restrict__ Wc,
    const float* __restrict__ bias,
    const float* __restrict__ g1w, const float* __restrict__ g1b,
    const float* __restrict__ g1S, const float* __restrict__ g1Q,
    float* __restrict__ outN,
    float* __restrict__ gnS, float* __restrict__ gnQ) {
    __shared__ __align__(16) char lds[CLDS];
    __shared__ float chA[128], chB[128];
    const int h = blockIdx.x & 1;
    const int y = blockIdx.x >> 1;
    const int n = blockIdx.y;
    const int tid = threadIdx.x;

    if (tid < 128) {   // GN1 per-channel affine: act = silu(v*A + B)
        const int ch = tid, grp = tid >> 2;
        const float s1 = g1S[n * 32 + grp] + g1S[256 + n * 32 + grp];
        const float q1 = g1Q[n * 32 + grp] + g1Q[256 + n * 32 + grp];
        const float mu = s1 * (1.f / 16384.f);
        const float var = q1 * (1.f / 16384.f) - mu * mu;
        const float rstd = rsqrtf(var + EPS_);
        const float A = g1w[ch] * rstd;
        chA[ch] = A;
        chB[ch] = g1b[ch] - mu * A;
    }
    __syncthreads();

    // staging: units (r, cp, s4): px quad at px0 = 32h-4+4*s4, ch pair 2cp
    union F4 { float4 v; float f[4]; };
#pragma unroll
    for (int u = 0; u < 8; ++u) {
        int idx = u * 256 + tid;
        if (idx < 1920) {
            int r = idx / 640, rem = idx - r * 640;
            int cp = rem / 10, s4 = rem - cp * 10;
            int ch0 = 2 * cp;
            int yy = y - 1 + r;
            int px0 = 32 * h - 4 + 4 * s4;
            char* dst0 = lds + (r * TW + 4 * s4) * COLB + 4 * cp;
            if (yy >= 0 && yy < 64 && px0 >= 0 && px0 < 61) {
                const float* src = cin + (((size_t)(n * C_ + ch0)) << 12) + yy * 64 + px0;
                F4 fa, fb;
                fa.v = *(const float4*)src;
                fb.v = *(const float4*)(src + HW_);
                const float A0 = chA[ch0], B0 = chB[ch0];
                const float A1 = chA[ch0 + 1], B1 = chB[ch0 + 1];
#pragma unroll
                for (int e = 0; e < 4; ++e) {
                    unsigned int lo = f2bf(silu(fa.f[e] * A0 + B0));
                    unsigned int hi = f2bf(silu(fb.f[e] * A1 + B1));
                    *(unsigned int*)(dst0 + e * COLB) = lo | (hi << 16);
                }
            } else {
#pragma unroll
                for (int e = 0; e < 4; ++e)
                    *(unsigned int*)(dst0 + e * COLB) = 0u;
            }
        }
    }
    __syncthreads();

    const int og = tid >> 6;   // och group (32 ch)
    const int l = tid & 63;
    const int lm = l & 31;     // px within half
    const int lh = l >> 5;

    v16f acc;
#pragma unroll
    for (int i = 0; i < 16; ++i) acc[i] = 0.f;

#pragma unroll
    for (int kk = 0; kk < 9; ++kk) {
        const int r = kk / 3, dx = kk % 3 - 1;
        const char* col = lds + (r * TW + lm + 4 + dx) * COLB + 16 * lh;
        const unsigned short* wbase = Wc + (size_t)(kk * 16 + lh) * C_ * 8 + (32 * og + lm) * 8;
#pragma unroll
        for (int cb = 0; cb < 8; ++cb) {
            v8s a = *(const v8s*)(wbase + (size_t)(2 * cb) * C_ * 8);
            v8s b = *(const v8s*)(col + 32 * cb);
            acc = __builtin_amdgcn_mfma_f32_32x32x16_bf16(a, b, acc, 0, 0, 0);
        }
    }
    __syncthreads();   // tile consumed; reuse for transpose + stats
    float* ldsT = (float*)lds;                        // [32 px][TSTRIDE]
    float* ldsS = (float*)(lds + 32 * TSTRIDE * 4);   // 128
    float* ldsQ = ldsS + 128;                         // 128
#pragma unroll
    for (int r = 0; r < 16; ++r) {
        const int row = (r & 3) + 8 * (r >> 2) + 4 * lh;
        const int co = 32 * og + row;
        float v = acc[r] + bias[co];
        ldsT[lm * TSTRIDE + co] = v;
        float p = v, q = v * v;
#pragma unroll
        for (int m = 16; m > 0; m >>= 1) {
            p += __shfl_xor(p, m, 64);
            q += __shfl_xor(q, m, 64);
        }
        if (lm == 0) { ldsS[co] = p; ldsQ[co] = q; }
    }
    __syncthreads();
    if (tid < 32) {
        const int g = tid;
        float p = ldsS[4 * g] + ldsS[4 * g + 1] + ldsS[4 * g + 2] + ldsS[4 * g + 3];
        float q = ldsQ[4 * g] + ldsQ[4 * g + 1] + ldsQ[4 * g + 2] + ldsQ[4 * g + 3];
        atomicAdd(&gnS[n * 32 + g], p);
        atomicAdd(&gnQ[n * 32 + g], q);
    }
    // coalesced NHWC store: 32 px x 128 ch
    const int q4 = tid & 31;
    float* orow = outN + (((size_t)(n * HW_) + (y << 6) + 32 * h) << 7);
#pragma unroll
    for (int it = 0; it < 4; ++it) {
        const int px = it * 8 + (tid >> 5);
        *(float4*)(orow + ((size_t)px << 7) + 4 * q4) =
            *(const float4*)(ldsT + px * TSTRIDE + 4 * q4);
    }
}

// ---- conv2: half-row tile; GN2+FiLM+SiLU staging from NHWC y; MFMA;
//      sign slab + pool. block = (y*2+h, n). ----
__global__ __launch_bounds__(256, 4) void k_conv2(
    const float* __restrict__ yin,  // NHWC
    const unsigned short* __restrict__ Wc,
    const float* __restrict__ bias,
    const float* __restrict__ res,
    const float* __restrict__ xin,
    const float* __restrict__ b1v,
    const float* __restrict__ eo,
    const float* __restrict__ g2,
    const float* __restrict__ bt2,
    const float* __restrict__ gnS,
    const float* __restrict__ gnQ,
    float* __restrict__ poolC2,
    int8_t* __restrict__ S) {
    __shared__ __align__(16) char lds[CLDS];
    __shared__ float ldsA[128], ldsB[128];
    const int h = blockIdx.x & 1;
    const int y = blockIdx.x >> 1;
    const int n = blockIdx.y;
    const int tid = threadIdx.x;

    if (tid < 128) {
        const int ch = tid, grp = tid >> 2;
        const float mu = gnS[n * 32 + grp] * (1.f / 16384.f);
        const float var = gnQ[n * 32 + grp] * (1.f / 16384.f) - mu * mu;
        const float rstd = rsqrtf(var + EPS_);
        const float gg = g2[ch] * rstd;
        const float sc = 1.f + eo[n * 256 + ch];
        ldsA[ch] = gg * sc;
        ldsB[ch] = (bt2[ch] - mu * gg) * sc + eo[n * 256 + 128 + ch];
    }
    __syncthreads();

    // staging: units (r, t, qc): px = 32h-4+t, channel quad 4qc
#pragma unroll
    for (int u = 0; u < 15; ++u) {
        int idx = u * 256 + tid;       // < 3840
        int r = idx / 1280, rem = idx - r * 1280;
        int t = rem >> 5, qc = rem & 31;
        int yy = y - 1 + r;
        int px = 32 * h - 4 + t;
        char* dst = lds + (r * TW + t) * COLB + qc * 8;
        if (yy >= 0 && yy < 64 && px >= 0 && px < 64) {
            const float* ysrc = yin + (((size_t)(n * HW_) + yy * 64 + px) << 7);
            float4 v = *(const float4*)(ysrc + 4 * qc);
            union { unsigned short u[4]; uint2 q; } pk;
            pk.u[0] = f2bf(silu(v.x * ldsA[4 * qc]     + ldsB[4 * qc]));
            pk.u[1] = f2bf(silu(v.y * ldsA[4 * qc + 1] + ldsB[4 * qc + 1]));
            pk.u[2] = f2bf(silu(v.z * ldsA[4 * qc + 2] + ldsB[4 * qc + 2]));
            pk.u[3] = f2bf(silu(v.w * ldsA[4 * qc + 3] + ldsB[4 * qc + 3]));
            *(uint2*)dst = pk.q;
        } else {
            *(uint2*)dst = make_uint2(0u, 0u);
        }
    }
    __syncthreads();

    const int og = tid >> 6;
    const int l = tid & 63;
    const int lm = l & 31;
    const int lh = l >> 5;

    v16f acc;
#pragma unroll
    for (int i = 0; i < 16; ++i) acc[i] = 0.f;

#pragma unroll
    for (int kk = 0; kk < 9; ++kk) {
        const int r = kk / 3, dx = kk % 3 - 1;
        const char* col = lds + (r * TW + lm + 4 + dx) * COLB + 16 * lh;
        const unsigned short* wbase = Wc + (size_t)(kk * 16 + lh) * C_ * 8 + (32 * og + lm) * 8;
#pragma unroll
        for (int cb = 0; cb < 8; ++cb) {
            v8s a = *(const v8s*)(wbase + (size_t)(2 * cb) * C_ * 8);
            v8s b = *(const v8s*)(col + 32 * cb);
            acc = __builtin_amdgcn_mfma_f32_32x32x16_bf16(a, b, acc, 0, 0, 0);
        }
    }
    float c2v[16];
#pragma unroll
    for (int r = 0; r < 16; ++r) {
        const int row = (r & 3) + 8 * (r >> 2) + 4 * lh;
        const int co = 32 * og + row;
        const size_t o = (((size_t)n * C_ + co) << 12) + (y << 6) + 32 * h;
        c2v[r] = acc[r] + bias[co] + res[o + lm];
    }
    // pooled c2-half (channel-pair means)
#pragma unroll
    for (int q = 0; q < 4; ++q) {
        const int pc = 16 * og + 4 * q + 2 * lh;   // pooled channel (0..63)
        const size_t po = (((size_t)n * 64 + pc) << 12) + (y << 6) + 32 * h;
        poolC2[po + lm]        = 0.5f * (c2v[4 * q] + c2v[4 * q + 1]);
        poolC2[po + 4096 + lm] = 0.5f * (c2v[4 * q + 2] + c2v[4 * q + 3]);
    }

    // sign slab: h=0 -> S cols 0..32 (col0 guard), h=1 -> cols 33..65 (col65
    // guard). Slab col s = global col - cb0; data col for px = 32h+lm is
    // s = lm + 1 - h.
    __syncthreads();
#pragma unroll
    for (int q = 0; q < 4; ++q) {
        const int co0 = 32 * og + 8 * q + 4 * lh;
        const float b0 = b1v[n * 256 + 128 + co0];
        const float b1b = b1v[n * 256 + 128 + co0 + 1];
        const float b2b = b1v[n * 256 + 128 + co0 + 2];
        const float b3b = b1v[n * 256 + 128 + co0 + 3];
        union { int8_t b[4]; int u; } p0;
        p0.b[0] = sgn8(c2v[4 * q] + b0);
        p0.b[1] = sgn8(c2v[4 * q + 1] + b1b);
        p0.b[2] = sgn8(c2v[4 * q + 2] + b2b);
        p0.b[3] = sgn8(c2v[4 * q + 3] + b3b);
        *(int*)(lds + (lm + 1 - h) * COLB + 128 + co0) = p0.u;
    }
#pragma unroll
    for (int u = 0; u < 4; ++u) {
        int idx = u * 256 + tid;       // < 1024 = 128 ch x 8 px-quads
        int ch = idx >> 3, sg = idx & 7;
        float4 v = *(const float4*)(xin + (((size_t)(n * C_ + ch)) << 12) + (y << 6) + 32 * h + 4 * sg);
        const float bv = b1v[n * 256 + ch];
        const int s0 = 4 * sg + 1 - h;
        lds[(s0)     * COLB + ch] = sgn8(v.x + bv);
        lds[(s0 + 1) * COLB + ch] = sgn8(v.y + bv);
        lds[(s0 + 2) * COLB + ch] = sgn8(v.z + bv);
        lds[(s0 + 3) * COLB + ch] = sgn8(v.w + bv);
    }
    if (tid < 17) {   // zero guard col: h=0 slab s=0, h=1 slab s=32
        const int s = h ? 32 : 0;
        *(float4*)(lds + s * COLB + tid * 16) = make_float4(0.f, 0.f, 0.f, 0.f);
    }
    __syncthreads();
    const int cb0 = h ? 33 : 0;
    int8_t* Sdst = S + (size_t)n * 66 * ROWB + (size_t)(y + 1) * ROWB + (size_t)cb0 * COLB;
#pragma unroll
    for (int u = 0; u < 3; ++u) {
        int idx = u * 256 + tid;
        if (idx < 561)    // 33 cols * 272 / 16
            *(int4*)(Sdst + idx * 16) = *(const int4*)(lds + idx * 16);
    }
}

// ---- binary conv: half-row, async gload_lds staging + i8 MFMA + BN stats ----
__global__ __launch_bounds__(256, 5) void k_bconv(
    const int8_t* __restrict__ S,
    const int8_t* __restrict__ Wk,
    const float* __restrict__ alpha,
    const float* __restrict__ bias,
    float* __restrict__ out,
    float* __restrict__ bnS, float* __restrict__ bnQ) {
    __shared__ __align__(16) char lds[3 * BROW];
    const int h = blockIdx.x & 1;
    const int y = blockIdx.x >> 1;
    const int n = blockIdx.y;
    const int tid = threadIdx.x;
    // rows y-1..y+1 (guard-indexed rows y..y+2), cols from 32h
    const char* sb = (const char*)S + (size_t)n * 66 * ROWB + (size_t)y * ROWB
                     + (size_t)(32 * h) * COLB;
    const int wave = tid >> 6, lane = tid & 63;
#pragma unroll
    for (int r = 0; r < 3; ++r)
        for (int j = wave; j < 10; j += 4)
            gld16(lds + r * BROW + j * 1024, sb + (size_t)r * ROWB + j * 1024 + lane * 16);
    __syncthreads();

    const int og = tid >> 6;
    const int l = tid & 63;
    const int lm = l & 31;
    const int lh = l >> 5;

    v16i acc;
#pragma unroll
    for (int i = 0; i < 16; ++i) acc[i] = 0;

#pragma unroll
    for (int kk = 0; kk < 9; ++kk) {
        const int r = kk / 3, dx = kk % 3 - 1;
        const char* col = lds + r * BROW + (lm + dx + 1) * COLB + 16 * lh;
        const int8_t* wbase = Wk + (size_t)(kk * 16 + lh) * C_ * 16 + (32 * og + lm) * 16;
#pragma unroll
        for (int s = 0; s < 8; ++s) {
            v4i a = *(const v4i*)(wbase + (size_t)(2 * s) * C_ * 16);
            v4i b = *(const v4i*)(col + 32 * s);
            acc = __builtin_amdgcn_mfma_i32_32x32x32_i8(a, b, acc, 0, 0, 0);
        }
    }
    __syncthreads();   // staging consumed; reuse LDS for stats
    float* ldsS = (float*)lds;          // 128
    float* ldsQ = (float*)lds + 128;    // 128
#pragma unroll
    for (int r = 0; r < 16; ++r) {
        const int row = (r & 3) + 8 * (r >> 2) + 4 * lh;
        const int co = 32 * og + row;
        const float av = alpha[co], bv = bias[co];
        const size_t o = (((size_t)n * C_ + co) << 12) + (y << 6) + 32 * h;
        float v = av * (float)acc[r] + bv;
        out[o + lm] = v;
        float p = v, q = v * v;
#pragma unroll
        for (int m = 16; m > 0; m >>= 1) {
            p += __shfl_xor(p, m, 64);
            q += __shfl_xor(q, m, 64);
        }
        if (lm == 0) { ldsS[co] = p; ldsQ[co] = q; }
    }
    __syncthreads();
    if (tid < 128) {
        atomicAdd(&bnS[tid], ldsS[tid]);
        atomicAdd(&bnQ[tid], ldsQ[tid]);
    }
}

// ---- final epilogue, float4 ----
__global__ __launch_bounds__(256) void k_final(const float* __restrict__ y3,
                                               const float* __restrict__ x,
                                               const float* __restrict__ poolC2,
                                               const float* __restrict__ bnS,
                                               const float* __restrict__ bnQ,
                                               const float* __restrict__ bng,
                                               const float* __restrict__ bnb,
                                               const float* __restrict__ b2v,
                                               const float* __restrict__ pa,
                                               const float* __restrict__ b3v,
                                               float* __restrict__ out) {
    const int idx4 = blockIdx.x * 256 + threadIdx.x;   // < 1,048,576
    const int hw = (idx4 & 1023) * 4;
    const int cb = idx4 >> 10;
    const int co = cb & 127;
    const int n = cb >> 7;
    const float mu = bnS[co] * (1.f / 32768.f);
    const float var = bnQ[co] * (1.f / 32768.f) - mu * mu;
    const float rstd = rsqrtf(var + EPS_);
    const float gm = rstd * bng[co];
    const float bt = bnb[co] - mu * gm;
    const size_t obase = (((size_t)(n * C_ + co)) << 12) + hw;
    float4 v = *(const float4*)(y3 + obase);
    v.x = v.x * gm + bt; v.y = v.y * gm + bt; v.z = v.z * gm + bt; v.w = v.w * gm + bt;

    float4 pv;
    if (co < 64) {
        const int ch0 = 2 * co;
        float4 pA = *(const float4*)(x + (((size_t)(n * C_ + ch0)) << 12) + hw);
        float4 pB = *(const float4*)(x + (((size_t)(n * C_ + ch0 + 1)) << 12) + hw);
        pv.x = 0.5f * (pA.x + pB.x); pv.y = 0.5f * (pA.y + pB.y);
        pv.z = 0.5f * (pA.z + pB.z); pv.w = 0.5f * (pA.w + pB.w);
    } else {
        pv = *(const float4*)(poolC2 + (((size_t)(n * 64 + co - 64)) << 12) + hw);
    }
    const float bias2 = b2v[n * 128 + co];
    const float aP = pa[co];
    const float bias3 = b3v[n * 128 + co];
    float4 r;
    float t;
    t = v.x + pv.x + bias2; t = (t >= 0.f) ? t : aP * t; r.x = t + bias3;
    t = v.y + pv.y + bias2; t = (t >= 0.f) ? t : aP * t; r.y = t + bias3;
    t = v.z + pv.z + bias2; t = (t >= 0.f) ? t : aP * t; r.z = t + bias3;
    t = v.w + pv.w + bias2; t = (t >= 0.f) ? t : aP * t; r.w = t + bias3;
    *(float4*)(out + obase) = r;
}

// ---------------- launch ----------------
extern "C" void kernel_launch(void* const* d_in, const int* in_sizes, int n_in,
                              void* d_out, int out_size, void* d_ws, size_t ws_size,
                              hipStream_t stream) {
    const float* c       = (const float*)d_in[0];
    const float* x       = (const float*)d_in[1];
    const float* emb     = (const float*)d_in[2];
    const float* gn1_g   = (const float*)d_in[3];
    const float* gn1_b   = (const float*)d_in[4];
    const float* conv1_w = (const float*)d_in[5];
    const float* conv1_b = (const float*)d_in[6];
    const float* emb_w   = (const float*)d_in[7];
    const float* emb_b   = (const float*)d_in[8];
    const float* gn2_g   = (const float*)d_in[9];
    const float* gn2_b   = (const float*)d_in[10];
    const float* conv2_w = (const float*)d_in[11];
    const float* conv2_b = (const float*)d_in[12];
    const float* m1_w    = (const float*)d_in[13];
    const float* m1_b    = (const float*)d_in[14];
    const float* bconv_w = (const float*)d_in[15];
    const float* bconv_b = (const float*)d_in[16];
    const float* bn_g    = (const float*)d_in[17];
    const float* bn_b    = (const float*)d_in[18];
    const float* m2_w    = (const float*)d_in[19];
    const float* m2_b    = (const float*)d_in[20];
    const float* prelu_a = (const float*)d_in[21];
    const float* m3_w    = (const float*)d_in[22];
    const float* m3_b    = (const float*)d_in[23];
    float* out = (float*)d_out;

    float* ws = (float*)d_ws;
    const size_t NCHW = (size_t)B_ * C_ * HW_;       // 4,194,304
    float*  poolC2 = ws;
    float*  y_buf = ws + NCHW;          // conv1 NHWC fp32, later bconv NCHW out
    int8_t* S     = (int8_t*)(ws + 2 * NCHW);   // padded: 8 x 66 x ROWB
    const size_t S_f = (8 * 66 * (size_t)ROWB) / 4 + 512;   // floats, +2KB slack
    int8_t* sgn   = (int8_t*)(ws + 2 * NCHW + S_f);
    unsigned short* Wc1 = (unsigned short*)(ws + 2 * NCHW + S_f + 73728);
    unsigned short* Wc2 = Wc1 + C_ * C_ * 9;
    float*  alpha = ws + 2 * NCHW + S_f + 73728 + 2 * 73728;
    float*  eo    = alpha + 128;
    float*  b1v   = eo + B_ * 256;
    float*  b2v   = b1v + B_ * 256;
    float*  b3v   = b2v + B_ * 128;
    float*  bnS   = b3v + B_ * 128;
    float*  bnQ   = bnS + 128;
    float*  gnS   = bnQ + 128;   // 256
    float*  gnQ   = gnS + 256;   // 256
    float*  g1S   = gnQ + 256;   // 512 (two halves)
    float*  g1Q   = g1S + 512;   // 512

    k_prep<<<1424, 256, 0, stream>>>(bconv_w, sgn, alpha, bnS, bnQ, gnS, gnQ,
                                     conv1_w, conv2_w, Wc1, Wc2,
                                     emb, emb_w, emb_b, m1_w, m1_b, m2_w, m2_b,
                                     m3_w, m3_b, eo, b1v, b2v, b3v,
                                     c, g1S, g1Q, S);
    k_conv1<<<dim3(128, B_), 256, 0, stream>>>(c, Wc1, conv1_b, gn1_g, gn1_b,
                                               g1S, g1Q, y_buf, gnS, gnQ);
    k_conv2<<<dim3(128, B_), 256, 0, stream>>>(y_buf, Wc2, conv2_b, c, x, b1v, eo,
                                               gn2_g, gn2_b, gnS, gnQ, poolC2, S);
    k_bconv<<<dim3(128, B_), 256, 0, stream>>>(S, sgn, alpha, bconv_b, y_buf, bnS, bnQ);
    k_final<<<NCHW / 1024, 256, 0, stream>>>(y_buf, x, poolC2, bnS, bnQ, bn_g, bn_b,
                                             b2v, prelu_a, b3v, out);
}

// Round 11
// 207.055 us; speedup vs baseline: 1.1534x; 1.1534x over previous
//
#include <hip/hip_runtime.h>
#include <stdint.h>

// ConcatLayer_55654186221983 on MI355X (gfx950). All fp32 I/O.
// B=8, C=128, C2=256, H=W=64, EMB=512, GROUPS=32, EPS=1e-5.
// R20: R18/R19's 71KB-LDS bconv killed the container twice (static LDS >64KB
//      per workgroup = unvalidated opt-in on this harness). Revert bconv
//      staging to R15's proven 3-guard-row gload_lds (54KB). KEEP the safe
//      half of the experiment: de-contended per-n BN-stat slabs bnP[n][128]
//      (64 adds/addr vs 512), summed in k_final. Else R15-verbatim.

#define B_   8
#define C_   128
#define C2_  256
#define HW_  4096
#define EMB_ 512
#define EPS_ 1e-5f

typedef int   v16i __attribute__((ext_vector_type(16)));
typedef float v16f __attribute__((ext_vector_type(16)));
typedef short v8s  __attribute__((ext_vector_type(8)));
typedef int   v4i  __attribute__((ext_vector_type(4)));

// LDS tile: 3 rows x 66 cols x (256 data + 16 pad) bytes
#define COLB 272
#define ROWB (66 * COLB)          // 17952 B per padded S row
#define LDSZ 55296                // 54 KB (proven in R15)
#define TSTRIDE 132

__device__ __forceinline__ float silu(float v) {
    return v * __builtin_amdgcn_rcpf(1.f + __expf(-v));
}
__device__ __forceinline__ unsigned short f2bf(float f) {
    unsigned int x = __float_as_uint(f);
    return (unsigned short)((x + 0x7FFFu + ((x >> 16) & 1u)) >> 16);  // RNE
}
__device__ __forceinline__ int8_t sgn8(float v) {
    return (v > 0.f) ? (int8_t)1 : ((v < 0.f) ? (int8_t)(-1) : (int8_t)0);
}
__device__ __forceinline__ void gld16(char* ldst, const char* gsrc) {
    __builtin_amdgcn_global_load_lds((const unsigned int*)gsrc,
                                     (unsigned int*)ldst, 16, 0, 0);
}

// ---- merged prep + embedding + GN1-stats-halves + S-guard-zero ----
__global__ __launch_bounds__(256) void k_prep(
    const float* __restrict__ w, int8_t* __restrict__ sgn,
    float* __restrict__ alpha, float* __restrict__ bnPS, float* __restrict__ bnPQ,
    float* __restrict__ gnS, float* __restrict__ gnQ,
    const float* __restrict__ w1, const float* __restrict__ w2,
    unsigned short* __restrict__ Wc1, unsigned short* __restrict__ Wc2,
    const float* __restrict__ emb,
    const float* __restrict__ ew, const float* __restrict__ ebb,
    const float* __restrict__ m1w, const float* __restrict__ m1b,
    const float* __restrict__ m2w, const float* __restrict__ m2b,
    const float* __restrict__ m3w, const float* __restrict__ m3b,
    float* __restrict__ eo, float* __restrict__ b1,
    float* __restrict__ b2, float* __restrict__ b3,
    const float* __restrict__ gin,
    float* __restrict__ g1S, float* __restrict__ g1Q,
    int8_t* __restrict__ S) {
    __shared__ float red[256];
    const int blk = blockIdx.x, tid = threadIdx.x;
    if (blk < 128) {
        const int o = blk;
        if (o == 0) {
            for (int i = tid; i < 1024; i += 256) { bnPS[i] = 0.f; bnPQ[i] = 0.f; }
        }
        if (o == 1) { gnS[tid] = 0.f; }
        if (o == 2) { gnQ[tid] = 0.f; }
        const float* wr = w + (size_t)o * (C2_ * 9);
        float s = 0.f;
        for (int i = tid; i < C2_ * 9; i += 256) s += fabsf(wr[i]);
        red[tid] = s;
        __syncthreads();
        for (int st = 128; st > 0; st >>= 1) {
            if (tid < st) red[tid] += red[tid + st];
            __syncthreads();
        }
        if (tid == 0) alpha[o] = red[0] / (float)(C2_ * 9);
        for (int kk = 0; kk < 9; ++kk) {
            float v = wr[tid * 9 + kk];   // tid == ci
            sgn[((size_t)(kk * 16 + (tid >> 4)) * C_ + o) * 16 + (tid & 15)] = sgn8(v);
        }
    } else if (blk < 704) {
        int i = (blk - 128) * 256 + tid;
        int co = i / (C_ * 9);
        int rem = i - co * (C_ * 9);
        int ci = rem / 9, kk = rem - ci * 9;
        size_t d = ((size_t)(kk * 16 + (ci >> 3)) * C_ + co) * 8 + (ci & 7);
        Wc1[d] = f2bf(w1[i]);
        Wc2[d] = f2bf(w2[i]);
    } else if (blk < 896) {
        const int o = (blk - 704) * 4 + (tid >> 6);   // 0..767
        const int l = tid & 63;
        const float* wv;
        float bias;
        float* dst;
        int dstride;
        if (o < 256)      { wv = ew  + (size_t)o * EMB_;              bias = ebb[o];    dst = eo + o;  dstride = 256; }
        else if (o < 512) { int r = o - 256; wv = m1w + (size_t)r * EMB_; bias = m1b[r]; dst = b1 + r; dstride = 256; }
        else if (o < 640) { int r = o - 512; wv = m2w + (size_t)r * EMB_; bias = m2b[r]; dst = b2 + r; dstride = 128; }
        else              { int r = o - 640; wv = m3w + (size_t)r * EMB_; bias = m3b[r]; dst = b3 + r; dstride = 128; }
        const float4 wa = *(const float4*)(wv + 8 * l);
        const float4 wb = *(const float4*)(wv + 8 * l + 4);
#pragma unroll
        for (int b = 0; b < B_; ++b) {
            const float* s = emb + b * EMB_ + 8 * l;
            float4 sa = *(const float4*)(s);
            float4 sb = *(const float4*)(s + 4);
            float p = wa.x * silu(sa.x) + wa.y * silu(sa.y) + wa.z * silu(sa.z) + wa.w * silu(sa.w) +
                      wb.x * silu(sb.x) + wb.y * silu(sb.y) + wb.z * silu(sb.z) + wb.w * silu(sb.w);
#pragma unroll
            for (int off = 32; off > 0; off >>= 1) p += __shfl_down(p, off, 64);
            if (l == 0) dst[b * dstride] = bias + p;
        }
    } else if (blk < 1408) {
        // GN1 stats, hw-halves: block = (n, grp, h); conv1 sums both parts
        const int idx = blk - 896;
        const int n = idx >> 6, rest = idx & 63, grp = rest >> 1, h = rest & 1;
        const size_t base = ((size_t)(n * C_ + grp * 4)) << 12;
        float sum = 0.f, sq = 0.f;
        const float4* in4 = (const float4*)(gin + base);
        for (int i = tid + h * 2048; i < (h + 1) * 2048; i += 256) {
            float4 v = in4[i];
            sum += v.x + v.y + v.z + v.w;
            sq += v.x * v.x + v.y * v.y + v.z * v.z + v.w * v.w;
        }
#pragma unroll
        for (int off = 32; off > 0; off >>= 1) {
            sum += __shfl_xor(sum, off, 64);
            sq  += __shfl_xor(sq, off, 64);
        }
        if ((tid & 63) == 0) { red[tid >> 6] = sum; red[8 + (tid >> 6)] = sq; }
        __syncthreads();
        if (tid == 0) {
            g1S[h * 256 + n * 32 + grp] = red[0] + red[1] + red[2] + red[3];
            g1Q[h * 256 + n * 32 + grp] = red[8] + red[9] + red[10] + red[11];
        }
    } else {
        // zero S guard rows (row 0 and row 65 per n)
        const int u = blk - 1408;       // 0..15
        const int n = u >> 1;
        const int row = (u & 1) * 65;
        int4* base = (int4*)(S + (size_t)n * 66 * ROWB + (size_t)row * ROWB);
        const int4 z = make_int4(0, 0, 0, 0);
        for (int i = tid; i < ROWB / 16; i += 256) base[i] = z;
    }
}

// ---- conv1: stages GN1+SiLU+bf16 from NCHW c (float4 loads, u32-pair
//      writes); bf16 MFMA; GN2 stats; writes y NHWC fp32. (R15 verbatim) ----
__global__ __launch_bounds__(512, 4) void k_conv1(
    const float* __restrict__ cin,
    const unsigned short* __restrict__ Wc,
    const float* __restrict__ bias,
    const float* __restrict__ g1w, const float* __restrict__ g1b,
    const float* __restrict__ g1S, const float* __restrict__ g1Q,
    float* __restrict__ outN,
    float* __restrict__ gnS, float* __restrict__ gnQ) {
    __shared__ __align__(16) char lds[LDSZ];
    __shared__ float chA[128], chB[128];
    const int y = blockIdx.x;
    const int n = blockIdx.y;
    const int tid = threadIdx.x;

    if (tid < 128) {   // GN1 per-channel affine: act = silu(v*A + B)
        const int ch = tid, grp = tid >> 2;
        const float s1 = g1S[n * 32 + grp] + g1S[256 + n * 32 + grp];
        const float q1 = g1Q[n * 32 + grp] + g1Q[256 + n * 32 + grp];
        const float mu = s1 * (1.f / 16384.f);
        const float var = q1 * (1.f / 16384.f) - mu * mu;
        const float rstd = rsqrtf(var + EPS_);
        const float A = g1w[ch] * rstd;
        chA[ch] = A;
        chB[ch] = g1b[ch] - mu * A;
    }
    if (tid < 96) {   // zero pad columns 0 and 65
        int r = tid / 32, q = tid & 31;
        int c = (q >> 4) ? 65 : 0, o = q & 15;
        *(float4*)(lds + (r * 66 + c) * COLB + o * 16) = make_float4(0.f, 0.f, 0.f, 0.f);
    }
    __syncthreads();

    union F4 { float4 v; float f[4]; };
#pragma unroll
    for (int u = 0; u < 6; ++u) {
        int unit = u * 512 + tid;        // 0..3071 = 3 x 64cp x 16s4
        int r = unit >> 10, rem = unit & 1023;
        int cp = rem >> 4, s4 = rem & 15;
        int ch0 = 2 * cp;
        int yy = y - 1 + r;
        char* dst0 = lds + (r * 66 + 4 * s4 + 1) * COLB + 4 * cp;
        if (yy >= 0 && yy < 64) {
            const float* src = cin + (((size_t)(n * C_ + ch0)) << 12) + yy * 64 + 4 * s4;
            F4 fa, fb;
            fa.v = *(const float4*)src;
            fb.v = *(const float4*)(src + HW_);
            const float A0 = chA[ch0], B0 = chB[ch0];
            const float A1 = chA[ch0 + 1], B1 = chB[ch0 + 1];
#pragma unroll
            for (int e = 0; e < 4; ++e) {
                unsigned int lo = f2bf(silu(fa.f[e] * A0 + B0));
                unsigned int hi = f2bf(silu(fb.f[e] * A1 + B1));
                *(unsigned int*)(dst0 + e * COLB) = lo | (hi << 16);
            }
        } else {
#pragma unroll
            for (int e = 0; e < 4; ++e)
                *(unsigned int*)(dst0 + e * COLB) = 0u;
        }
    }
    __syncthreads();

    const int w = tid >> 6;
    const int og = w >> 1;     // och group (32 ch)
    const int ph = w & 1;      // px half (32 px)
    const int l = tid & 63;
    const int lm = l & 31;
    const int lh = l >> 5;

    v16f acc;
#pragma unroll
    for (int i = 0; i < 16; ++i) acc[i] = 0.f;

#pragma unroll
    for (int kk = 0; kk < 9; ++kk) {
        const int r = kk / 3, dx = kk % 3 - 1;
        const char* col = lds + (r * 66 + 32 * ph + lm + 1 + dx) * COLB + 16 * lh;
        const unsigned short* wbase = Wc + (size_t)(kk * 16 + lh) * C_ * 8 + (32 * og + lm) * 8;
#pragma unroll
        for (int cb = 0; cb < 8; ++cb) {
            v8s a = *(const v8s*)(wbase + (size_t)(2 * cb) * C_ * 8);
            v8s b = *(const v8s*)(col + 32 * cb);
            acc = __builtin_amdgcn_mfma_f32_32x32x16_bf16(a, b, acc, 0, 0, 0);
        }
    }
    __syncthreads();   // staging LDS fully consumed; reuse for transpose+stats
    float* ldsT = (float*)lds;                        // [64][TSTRIDE]
    float* ldsS = (float*)(lds + 64 * TSTRIDE * 4);   // [2][128]
    float* ldsQ = ldsS + 256;                         // [2][128]
#pragma unroll
    for (int r = 0; r < 16; ++r) {
        const int row = (r & 3) + 8 * (r >> 2) + 4 * lh;
        const int co = 32 * og + row;
        float v = acc[r] + bias[co];
        ldsT[(32 * ph + lm) * TSTRIDE + co] = v;
        float p = v, q = v * v;
#pragma unroll
        for (int m = 16; m > 0; m >>= 1) {
            p += __shfl_xor(p, m, 64);
            q += __shfl_xor(q, m, 64);
        }
        if (lm == 0) { ldsS[ph * 128 + co] = p; ldsQ[ph * 128 + co] = q; }
    }
    __syncthreads();
    if (tid < 32) {
        const int g = tid;
        float p = 0.f, q = 0.f;
#pragma unroll
        for (int j = 0; j < 4; ++j) {
            p += ldsS[4 * g + j] + ldsS[128 + 4 * g + j];
            q += ldsQ[4 * g + j] + ldsQ[128 + 4 * g + j];
        }
        atomicAdd(&gnS[n * 32 + g], p);
        atomicAdd(&gnQ[n * 32 + g], q);
    }
    // coalesced NHWC store
    const int q4 = tid & 31;
    float* orow = outN + (((size_t)(n * HW_) + (y << 6)) << 7);
#pragma unroll
    for (int it = 0; it < 4; ++it) {
        const int px = it * 16 + (tid >> 5);
        *(float4*)(orow + ((size_t)px << 7) + 4 * q4) =
            *(const float4*)(ldsT + px * TSTRIDE + 4 * q4);
    }
}

// ---- conv2: stages GN2+FiLM+SiLU from NHWC fp32 y; MFMA; sign+pool;
//      writes S in padded LDS-image layout. (R15 verbatim) ----
__global__ __launch_bounds__(512, 4) void k_conv2(
    const float* __restrict__ yin,  // NHWC
    const unsigned short* __restrict__ Wc,
    const float* __restrict__ bias,
    const float* __restrict__ res,
    const float* __restrict__ xin,
    const float* __restrict__ b1v,
    const float* __restrict__ eo,
    const float* __restrict__ g2,
    const float* __restrict__ bt2,
    const float* __restrict__ gnS,
    const float* __restrict__ gnQ,
    float* __restrict__ poolC2,
    int8_t* __restrict__ S) {
    __shared__ __align__(16) char lds[LDSZ];
    __shared__ float ldsA[128], ldsB[128];
    const int y = blockIdx.x;
    const int n = blockIdx.y;
    const int tid = threadIdx.x;

    if (tid < 128) {
        const int ch = tid, grp = tid >> 2;
        const float mu = gnS[n * 32 + grp] * (1.f / 16384.f);
        const float var = gnQ[n * 32 + grp] * (1.f / 16384.f) - mu * mu;
        const float rstd = rsqrtf(var + EPS_);
        const float gg = g2[ch] * rstd;
        const float sc = 1.f + eo[n * 256 + ch];
        ldsA[ch] = gg * sc;
        ldsB[ch] = (bt2[ch] - mu * gg) * sc + eo[n * 256 + 128 + ch];
    }
    if (tid < 96) {
        int r = tid / 32, q = tid & 31;
        int cpad = (q >> 4) ? 65 : 0, o = q & 15;
        *(float4*)(lds + (r * 66 + cpad) * COLB + o * 16) = make_float4(0.f, 0.f, 0.f, 0.f);
    }
    __syncthreads();

    // staging from NHWC: thread owns channel-quad qc; affine coeffs hoisted
    const int qc = tid & 31;
    const float A0 = ldsA[4 * qc], A1 = ldsA[4 * qc + 1], A2 = ldsA[4 * qc + 2], A3 = ldsA[4 * qc + 3];
    const float B0 = ldsB[4 * qc], B1 = ldsB[4 * qc + 1], B2 = ldsB[4 * qc + 2], B3 = ldsB[4 * qc + 3];
#pragma unroll
    for (int r = 0; r < 3; ++r) {
        const int yy = y - 1 + r;
        const float* ysrc = yin + (((size_t)(n * HW_) + yy * 64) << 7);
        const bool ok = (yy >= 0 && yy < 64);
#pragma unroll
        for (int it = 0; it < 4; ++it) {
            const int px = it * 16 + (tid >> 5);
            char* dst = lds + (r * 66 + px + 1) * COLB + qc * 8;
            if (ok) {
                float4 v = *(const float4*)(ysrc + ((size_t)px << 7) + 4 * qc);
                union { unsigned short u[4]; uint2 q; } pk;
                pk.u[0] = f2bf(silu(v.x * A0 + B0));
                pk.u[1] = f2bf(silu(v.y * A1 + B1));
                pk.u[2] = f2bf(silu(v.z * A2 + B2));
                pk.u[3] = f2bf(silu(v.w * A3 + B3));
                *(uint2*)dst = pk.q;
            } else {
                *(uint2*)dst = make_uint2(0u, 0u);
            }
        }
    }
    __syncthreads();

    const int w = tid >> 6;
    const int og = w >> 1;
    const int ph = w & 1;
    const int l = tid & 63;
    const int lm = l & 31;
    const int lh = l >> 5;

    v16f acc;
#pragma unroll
    for (int i = 0; i < 16; ++i) acc[i] = 0.f;

#pragma unroll
    for (int kk = 0; kk < 9; ++kk) {
        const int r = kk / 3, dx = kk % 3 - 1;
        const char* col = lds + (r * 66 + 32 * ph + lm + 1 + dx) * COLB + 16 * lh;
        const unsigned short* wbase = Wc + (size_t)(kk * 16 + lh) * C_ * 8 + (32 * og + lm) * 8;
#pragma unroll
        for (int cb = 0; cb < 8; ++cb) {
            v8s a = *(const v8s*)(wbase + (size_t)(2 * cb) * C_ * 8);
            v8s b = *(const v8s*)(col + 32 * cb);
            acc = __builtin_amdgcn_mfma_f32_32x32x16_bf16(a, b, acc, 0, 0, 0);
        }
    }
    float c2v[16];
#pragma unroll
    for (int r = 0; r < 16; ++r) {
        const int row = (r & 3) + 8 * (r >> 2) + 4 * lh;
        const int co = 32 * og + row;
        const size_t o = (((size_t)n * C_ + co) << 12) + (y << 6);
        c2v[r] = acc[r] + bias[co] + res[o + 32 * ph + lm];
    }
    // pooled c2-half (channel-pair means)
#pragma unroll
    for (int q = 0; q < 4; ++q) {
        const int pc = 16 * og + 4 * q + 2 * lh;   // pooled channel (0..63)
        const size_t po = (((size_t)n * 64 + pc) << 12) + (y << 6);
        poolC2[po + 32 * ph + lm]        = 0.5f * (c2v[4 * q] + c2v[4 * q + 1]);
        poolC2[po + 4096 + 32 * ph + lm] = 0.5f * (c2v[4 * q + 2] + c2v[4 * q + 3]);
    }

    // fused sign: build padded S row image in LDS, then linear copy out
    __syncthreads();
#pragma unroll
    for (int q = 0; q < 4; ++q) {
        const int co0 = 32 * og + 8 * q + 4 * lh;
        const float b0 = b1v[n * 256 + 128 + co0];
        const float b1b = b1v[n * 256 + 128 + co0 + 1];
        const float b2b = b1v[n * 256 + 128 + co0 + 2];
        const float b3b = b1v[n * 256 + 128 + co0 + 3];
        union { int8_t b[4]; int u; } p0;
        p0.b[0] = sgn8(c2v[4 * q] + b0);
        p0.b[1] = sgn8(c2v[4 * q + 1] + b1b);
        p0.b[2] = sgn8(c2v[4 * q + 2] + b2b);
        p0.b[3] = sgn8(c2v[4 * q + 3] + b3b);
        *(int*)(lds + (32 * ph + lm + 1) * COLB + 128 + co0) = p0.u;
    }
#pragma unroll
    for (int u = 0; u < 4; ++u) {
        int idx = u * 512 + tid;
        int ch = idx >> 4, seg = idx & 15;
        float4 v = *(const float4*)(xin + (((size_t)(n * C_ + ch)) << 12) + (y << 6) + 4 * seg);
        const float bv = b1v[n * 256 + ch];
        lds[(4 * seg + 1) * COLB + ch] = sgn8(v.x + bv);
        lds[(4 * seg + 2) * COLB + ch] = sgn8(v.y + bv);
        lds[(4 * seg + 3) * COLB + ch] = sgn8(v.z + bv);
        lds[(4 * seg + 4) * COLB + ch] = sgn8(v.w + bv);
    }
    if (tid < 34) {   // zero columns 0 and 65 (17 x 16B each)
        int c = tid / 17, o = tid - c * 17;
        *(float4*)(lds + (c ? 65 : 0) * COLB + o * 16) = make_float4(0.f, 0.f, 0.f, 0.f);
    }
    __syncthreads();
    int4* Srow = (int4*)(S + (size_t)n * 66 * ROWB + (size_t)(y + 1) * ROWB);
    const int4* lsrc = (const int4*)lds;
    for (int i = tid; i < ROWB / 16; i += 512) Srow[i] = lsrc[i];
}

// ---- binary conv: async gload_lds staging (R15-verbatim, 54KB) + i8 MFMA +
//      per-n BN-stat slabs (de-contended) ----
__global__ __launch_bounds__(512, 2) void k_bconv(
    const int8_t* __restrict__ S,
    const int8_t* __restrict__ Wk,
    const float* __restrict__ alpha,
    const float* __restrict__ bias,
    float* __restrict__ out,
    float* __restrict__ bnPS, float* __restrict__ bnPQ) {
    __shared__ __align__(16) char lds[LDSZ];
    const int y = blockIdx.x;
    const int n = blockIdx.y;
    const int tid = threadIdx.x;
    // rows y-1..y+1 in guard space = contiguous 3*ROWB at row index y
    const char* src3 = (const char*)S + (size_t)n * 66 * ROWB + (size_t)y * ROWB;
    const int wave = tid >> 6, lane = tid & 63;
    for (int u = wave; u < 53; u += 8)      // 53*1024 >= 3*ROWB
        gld16(lds + u * 1024, src3 + u * 1024 + lane * 16);
    __syncthreads();

    const int w = tid >> 6;
    const int og = w >> 1;
    const int ph = w & 1;
    const int l = tid & 63;
    const int lm = l & 31;
    const int lh = l >> 5;

    v16i acc;
#pragma unroll
    for (int i = 0; i < 16; ++i) acc[i] = 0;

#pragma unroll
    for (int kk = 0; kk < 9; ++kk) {
        const int r = kk / 3, dx = kk % 3 - 1;
        const char* col = lds + (r * 66 + 32 * ph + lm + 1 + dx) * COLB + 16 * lh;
        const int8_t* wbase = Wk + (size_t)(kk * 16 + lh) * C_ * 16 + (32 * og + lm) * 16;
#pragma unroll
        for (int s = 0; s < 8; ++s) {
            v4i a = *(const v4i*)(wbase + (size_t)(2 * s) * C_ * 16);
            v4i b = *(const v4i*)(col + 32 * s);
            acc = __builtin_amdgcn_mfma_i32_32x32x32_i8(a, b, acc, 0, 0, 0);
        }
    }
    __syncthreads();   // staging consumed; reuse LDS for stats
    float* ldsS = (float*)lds;          // [2][128]
    float* ldsQ = (float*)lds + 256;    // [2][128]
#pragma unroll
    for (int r = 0; r < 16; ++r) {
        const int row = (r & 3) + 8 * (r >> 2) + 4 * lh;
        const int co = 32 * og + row;
        const float av = alpha[co], bv = bias[co];
        const size_t o = (((size_t)n * C_ + co) << 12) + (y << 6);
        float v = av * (float)acc[r] + bv;
        out[o + 32 * ph + lm] = v;
        float p = v, q = v * v;
#pragma unroll
        for (int m = 16; m > 0; m >>= 1) {
            p += __shfl_xor(p, m, 64);
            q += __shfl_xor(q, m, 64);
        }
        if (lm == 0) { ldsS[ph * 128 + co] = p; ldsQ[ph * 128 + co] = q; }
    }
    __syncthreads();
    if (tid < 128) {
        atomicAdd(&bnPS[n * 128 + tid], ldsS[tid] + ldsS[128 + tid]);
        atomicAdd(&bnPQ[n * 128 + tid], ldsQ[tid] + ldsQ[128 + tid]);
    }
}

// ---- final epilogue, float4; sums per-n BN slabs ----
__global__ __launch_bounds__(256) void k_final(const float* __restrict__ y3,
                                               const float* __restrict__ x,
                                               const float* __restrict__ poolC2,
                                               const float* __restrict__ bnPS,
                                               const float* __restrict__ bnPQ,
                                               const float* __restrict__ bng,
                                               const float* __restrict__ bnb,
                                               const float* __restrict__ b2v,
                                               const float* __restrict__ pa,
                                               const float* __restrict__ b3v,
                                               float* __restrict__ out) {
    const int idx4 = blockIdx.x * 256 + threadIdx.x;   // < 1,048,576
    const int hw = (idx4 & 1023) * 4;
    const int cb = idx4 >> 10;
    const int co = cb & 127;
    const int n = cb >> 7;
    float sS = 0.f, sQ = 0.f;
#pragma unroll
    for (int j = 0; j < 8; ++j) { sS += bnPS[j * 128 + co]; sQ += bnPQ[j * 128 + co]; }
    const float mu = sS * (1.f / 32768.f);
    const float var = sQ * (1.f / 32768.f) - mu * mu;
    const float rstd = rsqrtf(var + EPS_);
    const float gm = rstd * bng[co];
    const float bt = bnb[co] - mu * gm;
    const size_t obase = (((size_t)(n * C_ + co)) << 12) + hw;
    float4 v = *(const float4*)(y3 + obase);
    v.x = v.x * gm + bt; v.y = v.y * gm + bt; v.z = v.z * gm + bt; v.w = v.w * gm + bt;

    float4 pv;
    if (co < 64) {
        const int ch0 = 2 * co;
        float4 pA = *(const float4*)(x + (((size_t)(n * C_ + ch0)) << 12) + hw);
        float4 pB = *(const float4*)(x + (((size_t)(n * C_ + ch0 + 1)) << 12) + hw);
        pv.x = 0.5f * (pA.x + pB.x); pv.y = 0.5f * (pA.y + pB.y);
        pv.z = 0.5f * (pA.z + pB.z); pv.w = 0.5f * (pA.w + pB.w);
    } else {
        pv = *(const float4*)(poolC2 + (((size_t)(n * 64 + co - 64)) << 12) + hw);
    }
    const float bias2 = b2v[n * 128 + co];
    const float aP = pa[co];
    const float bias3 = b3v[n * 128 + co];
    float4 r;
    float t;
    t = v.x + pv.x + bias2; t = (t >= 0.f) ? t : aP * t; r.x = t + bias3;
    t = v.y + pv.y + bias2; t = (t >= 0.f) ? t : aP * t; r.y = t + bias3;
    t = v.z + pv.z + bias2; t = (t >= 0.f) ? t : aP * t; r.z = t + bias3;
    t = v.w + pv.w + bias2; t = (t >= 0.f) ? t : aP * t; r.w = t + bias3;
    *(float4*)(out + obase) = r;
}

// ---------------- launch ----------------
extern "C" void kernel_launch(void* const* d_in, const int* in_sizes, int n_in,
                              void* d_out, int out_size, void* d_ws, size_t ws_size,
                              hipStream_t stream) {
    const float* c       = (const float*)d_in[0];
    const float* x       = (const float*)d_in[1];
    const float* emb     = (const float*)d_in[2];
    const float* gn1_g   = (const float*)d_in[3];
    const float* gn1_b   = (const float*)d_in[4];
    const float* conv1_w = (const float*)d_in[5];
    const float* conv1_b = (const float*)d_in[6];
    const float* emb_w   = (const float*)d_in[7];
    const float* emb_b   = (const float*)d_in[8];
    const float* gn2_g   = (const float*)d_in[9];
    const float* gn2_b   = (const float*)d_in[10];
    const float* conv2_w = (const float*)d_in[11];
    const float* conv2_b = (const float*)d_in[12];
    const float* m1_w    = (const float*)d_in[13];
    const float* m1_b    = (const float*)d_in[14];
    const float* bconv_w = (const float*)d_in[15];
    const float* bconv_b = (const float*)d_in[16];
    const float* bn_g    = (const float*)d_in[17];
    const float* bn_b    = (const float*)d_in[18];
    const float* m2_w    = (const float*)d_in[19];
    const float* m2_b    = (const float*)d_in[20];
    const float* prelu_a = (const float*)d_in[21];
    const float* m3_w    = (const float*)d_in[22];
    const float* m3_b    = (const float*)d_in[23];
    float* out = (float*)d_out;

    float* ws = (float*)d_ws;
    const size_t NCHW = (size_t)B_ * C_ * HW_;       // 4,194,304
    float*  poolC2 = ws;
    float*  y_buf = ws + NCHW;          // conv1 NHWC fp32, later bconv NCHW out
    int8_t* S     = (int8_t*)(ws + 2 * NCHW);   // padded: 8 x 66 x ROWB
    const size_t S_f = (8 * 66 * (size_t)ROWB) / 4 + 512;   // floats, +2KB slack
    int8_t* sgn   = (int8_t*)(ws + 2 * NCHW + S_f);
    unsigned short* Wc1 = (unsigned short*)(ws + 2 * NCHW + S_f + 73728);
    unsigned short* Wc2 = Wc1 + C_ * C_ * 9;
    float*  alpha = ws + 2 * NCHW + S_f + 73728 + 2 * 73728;
    float*  eo    = alpha + 128;
    float*  b1v   = eo + B_ * 256;
    float*  b2v   = b1v + B_ * 256;
    float*  b3v   = b2v + B_ * 128;
    float*  bnPS  = b3v + B_ * 128;   // 1024 (per-n slabs)
    float*  bnPQ  = bnPS + 1024;      // 1024
    float*  gnS   = bnPQ + 1024;      // 256
    float*  gnQ   = gnS + 256;        // 256
    float*  g1S   = gnQ + 256;        // 512 (two halves)
    float*  g1Q   = g1S + 512;        // 512

    k_prep<<<1424, 256, 0, stream>>>(bconv_w, sgn, alpha, bnPS, bnPQ, gnS, gnQ,
                                     conv1_w, conv2_w, Wc1, Wc2,
                                     emb, emb_w, emb_b, m1_w, m1_b, m2_w, m2_b,
                                     m3_w, m3_b, eo, b1v, b2v, b3v,
                                     c, g1S, g1Q, S);
    k_conv1<<<dim3(64, B_), 512, 0, stream>>>(c, Wc1, conv1_b, gn1_g, gn1_b,
                                              g1S, g1Q, y_buf, gnS, gnQ);
    k_conv2<<<dim3(64, B_), 512, 0, stream>>>(y_buf, Wc2, conv2_b, c, x, b1v, eo,
                                              gn2_g, gn2_b, gnS, gnQ, poolC2, S);
    k_bconv<<<dim3(64, B_), 512, 0, stream>>>(S, sgn, alpha, bconv_b, y_buf,
                                              bnPS, bnPQ);
    k_final<<<NCHW / 1024, 256, 0, stream>>>(y_buf, x, poolC2, bnPS, bnPQ,
                                             bn_g, bn_b, b2v, prelu_a, b3v, out);
}